// Round 2
// baseline (88.635 us; speedup 1.0000x reference)
//
#include <hip/hip_runtime.h>
#include <math.h>

#define BB 16
#define NN 2048
#define MM 16
#define SS 128

__constant__ const float kFourPi = 12.566370614359172f;

// ---------------------------------------------------------------------------
// Kernel A: one block per (b,m), 1024 threads (16 waves), 1 block/CU.
// __launch_bounds__(1024, 4): 4 waves/EU min -> 128-VGPR cap.
//
// XCD-clustering swizzle (round 1): all 16 m-blocks of one b land on the
// same XCD; the 16 siblings read the SAME 192B pcl lines -> one HBM fetch,
// 15 L2 hits.
//
// NEW (this round):
//  (a) v_min3_f32 restructuring: s processed in pairs; d1 running-min as
//      min3(d1m, ea, eb); per-s n-trees as nested fminf triples.
//      VALU/pair 5.9 -> 5.0.
//  (b) T14 async-STAGE split: stage n-half-1 to LDS, ISSUE half-2 global
//      loads into regs, then raw lgkmcnt(0) + s_barrier (NOT __syncthreads,
//      which drains vmcnt(0) and would serialize the scatter loads). Half-2
//      loads fly under compute loop A (n in [0,1024)); written to the
//      disjoint LDS region after loop A, second raw barrier, loop B.
// ---------------------------------------------------------------------------
__global__ __launch_bounds__(1024, 4) void fused_dist_kernel(
    const float* __restrict__ pcl,    // (B,N,M,3)
    const float* __restrict__ prim,   // (B,M,S,3)
    float* __restrict__ d1,           // [256][2048]  (e-scale)
    float* __restrict__ d2sum,        // [256]        (d-scale)
    unsigned int* __restrict__ counter)
{
    // bi = {hi[7] | m[6:3] | xcd[2:0]};  b = xcd*2 + hi
    const int bi  = blockIdx.x;
    const int b   = ((bi & 7) << 1) | (bi >> 7);
    const int m   = (bi >> 3) & 15;
    const int bm  = (b << 4) | m;
    const int tid = threadIdx.x;

    __shared__ float  Qx[NN], Qy[NN], Qz[NN], Qh[NN];  // 32 KB
    __shared__ float4 Plds[SS];                        // 2 KB (x,y,z,hp)
    __shared__ float  d1s[4][NN];                      // 32 KB
    __shared__ float  wred[16][64];                    // 4 KB
    __shared__ float  rsum[4];

    if (bi == 0 && tid == 0)
        __hip_atomic_store(counter, 0u, __ATOMIC_RELAXED, __HIP_MEMORY_SCOPE_AGENT);

    // ---- phase 0: stage half-1 (n = tid) + prim; issue half-2 loads ----
    const size_t base = ((size_t)(b * NN) * MM + m) * 3;
    {
        const float* q = pcl + base + (size_t)tid * (MM * 3);
        const float x = q[0], y = q[1], z = q[2];
        Qx[tid] = x; Qy[tid] = y; Qz[tid] = z;
        Qh[tid] = 0.5f * (x * x + y * y + z * z);
    }
    if (tid < SS) {
        const float* pp = prim + ((size_t)bm * SS + tid) * 3;
        const float x = pp[0], y = pp[1], z = pp[2];
        Plds[tid] = make_float4(x, y, z, 0.5f * (x * x + y * y + z * z));
    }
    // half-2 loads issued now, consumed after loop A (T14 split)
    const float* q2p = pcl + base + (size_t)(tid + 1024) * (MM * 3);
    const float x2 = q2p[0], y2 = q2p[1], z2 = q2p[2];

    // raw barrier: drain LDS writes only, keep half-2 global loads in flight
    asm volatile("s_waitcnt lgkmcnt(0)" ::: "memory");
    __builtin_amdgcn_s_barrier();

    const int sub  = tid >> 8;    // s-chunk 0..3
    const int stid = tid & 255;
    const int s0   = sub * 32;
    const int wid  = tid >> 6;    // 0..15
    const int lane = tid & 63;

    float qx[4], qy[4], qz[4], hq[4];
    float d1mA[4], d1mB[4];
    float d2r[32];

    // ---- loop A: n in [0,1024)  (j = 0..3) ----
#pragma unroll
    for (int j = 0; j < 4; ++j) {
        const int n = stid + j * 256;
        qx[j] = Qx[n]; qy[j] = Qy[n]; qz[j] = Qz[n]; hq[j] = Qh[n];
        d1mA[j] = 3.0e38f;
    }
#pragma unroll
    for (int sp = 0; sp < 16; ++sp) {
        const float4 fa = Plds[s0 + 2 * sp];       // wave-uniform ds_read_b128
        const float4 fb = Plds[s0 + 2 * sp + 1];
        float ea[4], eb[4];
#pragma unroll
        for (int j = 0; j < 4; ++j) {
            float ta = hq[j] + fa.w;               // 0.5|q|^2 + 0.5|p|^2
            ta = fmaf(fa.x, -qx[j], ta);
            ta = fmaf(fa.y, -qy[j], ta);
            ta = fmaf(fa.z, -qz[j], ta);
            float tb = hq[j] + fb.w;
            tb = fmaf(fb.x, -qx[j], tb);
            tb = fmaf(fb.y, -qy[j], tb);
            tb = fmaf(fb.z, -qz[j], tb);
            ea[j] = ta; eb[j] = tb;
            d1mA[j] = fminf(d1mA[j], fminf(ta, tb));   // -> v_min3_f32
        }
        d2r[2 * sp]     = fminf(fminf(fminf(ea[0], ea[1]), ea[2]), ea[3]);
        d2r[2 * sp + 1] = fminf(fminf(fminf(eb[0], eb[1]), eb[2]), eb[3]);
    }

    // ---- write half-2 to LDS ([1024,2048): disjoint from loop A reads) ----
    Qx[tid + 1024] = x2; Qy[tid + 1024] = y2; Qz[tid + 1024] = z2;
    Qh[tid + 1024] = 0.5f * (x2 * x2 + y2 * y2 + z2 * z2);
    asm volatile("s_waitcnt lgkmcnt(0)" ::: "memory");
    __builtin_amdgcn_s_barrier();

    // ---- loop B: n in [1024,2048)  (j = 4..7) ----
#pragma unroll
    for (int j = 0; j < 4; ++j) {
        const int n = 1024 + stid + j * 256;
        qx[j] = Qx[n]; qy[j] = Qy[n]; qz[j] = Qz[n]; hq[j] = Qh[n];
        d1mB[j] = 3.0e38f;
    }
#pragma unroll
    for (int sp = 0; sp < 16; ++sp) {
        const float4 fa = Plds[s0 + 2 * sp];
        const float4 fb = Plds[s0 + 2 * sp + 1];
        float ea[4], eb[4];
#pragma unroll
        for (int j = 0; j < 4; ++j) {
            float ta = hq[j] + fa.w;
            ta = fmaf(fa.x, -qx[j], ta);
            ta = fmaf(fa.y, -qy[j], ta);
            ta = fmaf(fa.z, -qz[j], ta);
            float tb = hq[j] + fb.w;
            tb = fmaf(fb.x, -qx[j], tb);
            tb = fmaf(fb.y, -qy[j], tb);
            tb = fmaf(fb.z, -qz[j], tb);
            ea[j] = ta; eb[j] = tb;
            d1mB[j] = fminf(d1mB[j], fminf(ta, tb));   // -> v_min3_f32
        }
        d2r[2 * sp]     = fminf(fminf(fminf(fminf(ea[0], ea[1]), ea[2]), ea[3]),
                                d2r[2 * sp]);
        d2r[2 * sp + 1] = fminf(fminf(fminf(fminf(eb[0], eb[1]), eb[2]), eb[3]),
                                d2r[2 * sp + 1]);
    }

    // d1: combine 4 s-chunks in LDS, coalesced e-scale global write
#pragma unroll
    for (int j = 0; j < 4; ++j) {
        d1s[sub][stid + j * 256]        = d1mA[j];
        d1s[sub][1024 + stid + j * 256] = d1mB[j];
    }
    __syncthreads();
#pragma unroll
    for (int j = 0; j < 2; ++j) {
        const int n = tid + j * 1024;
        d1[(size_t)bm * NN + n] = fminf(fminf(d1s[0][n], d1s[1][n]),
                                        fminf(d1s[2][n], d1s[3][n]));
    }

    // --- d2: dimension-folding wave reduction (32 vals -> 1 per lane) ---
    float v16[16];
    {
        const bool hi = (lane & 32) != 0;
#pragma unroll
        for (int k = 0; k < 16; ++k) {
            const float xk = hi ? d2r[k + 16] : d2r[k];
            const float xs = hi ? d2r[k] : d2r[k + 16];
            v16[k] = fminf(xk, __shfl_xor(xs, 32, 64));
        }
    }
    float v8[8];
    {
        const bool hi = (lane & 16) != 0;
#pragma unroll
        for (int k = 0; k < 8; ++k) {
            const float xk = hi ? v16[k + 8] : v16[k];
            const float xs = hi ? v16[k] : v16[k + 8];
            v8[k] = fminf(xk, __shfl_xor(xs, 16, 64));
        }
    }
    float v4[4];
    {
        const bool hi = (lane & 8) != 0;
#pragma unroll
        for (int k = 0; k < 4; ++k) {
            const float xk = hi ? v8[k + 4] : v8[k];
            const float xs = hi ? v8[k] : v8[k + 4];
            v4[k] = fminf(xk, __shfl_xor(xs, 8, 64));
        }
    }
    float v2a, v2b;
    {
        const bool hi = (lane & 4) != 0;
        const float xk0 = hi ? v4[2] : v4[0];
        const float xs0 = hi ? v4[0] : v4[2];
        v2a = fminf(xk0, __shfl_xor(xs0, 4, 64));
        const float xk1 = hi ? v4[3] : v4[1];
        const float xs1 = hi ? v4[1] : v4[3];
        v2b = fminf(xk1, __shfl_xor(xs1, 4, 64));
    }
    float v1;
    {
        const bool hi = (lane & 2) != 0;
        const float xk = hi ? v2b : v2a;
        const float xs = hi ? v2a : v2b;
        v1 = fminf(xk, __shfl_xor(xs, 2, 64));
    }
    // lane holds min over its wave's 512 n for s = s0 + bits[5:1], dup x2
    const float r = fminf(v1, __shfl_xor(v1, 1, 64));
    wred[wid][lane] = r;
    __syncthreads();

    // combine the 4 waves of each sub-group (-> min over all 2048 n), clamp,
    // sum: 64-lane sum = 2 * sum_s e_min = sum_s d_min  (x2 dup cancels)
    if (tid < 256) {                 // waves 0..3, fully active
        const int sc = tid >> 6;     // s-chunk this wave combines
        const int l  = tid & 63;
        float mv = fminf(fminf(wred[sc * 4 + 0][l], wred[sc * 4 + 1][l]),
                         fminf(wred[sc * 4 + 2][l], wred[sc * 4 + 3][l]));
        if (mv >= 5.0e29f) mv = 0.0f;          // clamp at e-scale (d >= 1e30)
#pragma unroll
        for (int off = 32; off > 0; off >>= 1)
            mv += __shfl_down(mv, off, 64);
        if (l == 0) rsum[sc] = mv;
    }
    __syncthreads();
    if (tid == 0) d2sum[bm] = rsum[0] + rsum[1] + rsum[2] + rsum[3];
}

// ---------------------------------------------------------------------------
// Kernel B: p2p sort + stick-breaking; last block finalizes.
// grid 256 x 128 so all 256 CUs active; same b->XCD clustering as kernel A
// so d1 reads hit the writing XCD's L2. One thread per (b,n).
// ---------------------------------------------------------------------------
__global__ __launch_bounds__(128) void p2p_final_kernel(
    const float* __restrict__ d1,      // [256][2048] (e-scale)
    const float* __restrict__ probs,   // (B,M)
    const float* __restrict__ size_,   // (B,M,3)
    const float* __restrict__ d2sum,   // [256]
    float* __restrict__ partial,       // [256]
    unsigned int* __restrict__ counter,
    float* __restrict__ out)           // (4)
{
    const int tid = threadIdx.x;
    const int bi  = blockIdx.x;                  // 0..255
    const int b   = ((bi & 7) << 1) | (bi >> 7); // same b->XCD map as kernel A
    const int j   = (bi >> 3) & 15;
    const int n   = j * 128 + tid;

    float d[16], p[16];
#pragma unroll
    for (int m = 0; m < 16; ++m) {
        const float mn = d1[((size_t)(b * MM + m)) * NN + n];
        d[m] = mn + mn;                       // e -> d
    }

    const float* pb = probs + b * MM;
#pragma unroll
    for (int k = 0; k < 16; ++k) p[k] = pb[k];

#define CE(i, jj)                                             \
    {                                                         \
        const bool c = d[i] > d[jj];                          \
        const float td = c ? d[jj] : d[i];                    \
        d[jj] = c ? d[i] : d[jj];  d[i] = td;                 \
        const float tp = c ? p[jj] : p[i];                    \
        p[jj] = c ? p[i] : p[jj];  p[i] = tp;                 \
    }
#pragma unroll
    for (int r = 0; r < 16; ++r) {
        if ((r & 1) == 0) {
            CE(0, 1) CE(2, 3) CE(4, 5) CE(6, 7)
            CE(8, 9) CE(10, 11) CE(12, 13) CE(14, 15)
        } else {
            CE(1, 2) CE(3, 4) CE(5, 6) CE(7, 8)
            CE(9, 10) CE(11, 12) CE(13, 14)
        }
    }
#undef CE

    float acc = 1.0f, sum = 0.0f;
#pragma unroll
    for (int k = 0; k < 16; ++k) {
        sum += d[k] * p[k] * acc;
        acc *= (1.0f - p[k]);
    }

    const int wid  = tid >> 6;   // 0..1
    const int lane = tid & 63;
    __shared__ float red2[2];
#pragma unroll
    for (int off = 32; off > 0; off >>= 1)
        sum += __shfl_down(sum, off, 64);
    if (lane == 0) red2[wid] = sum;
    __syncthreads();

    __shared__ bool amLast;
    if (tid == 0) {
        const float bsum = red2[0] + red2[1];
        __hip_atomic_store(&partial[bi], bsum,
                           __ATOMIC_RELEASE, __HIP_MEMORY_SCOPE_AGENT);
        const unsigned int prev = __hip_atomic_fetch_add(
            counter, 1u, __ATOMIC_ACQ_REL, __HIP_MEMORY_SCOPE_AGENT);
        amLast = (prev == 255u);
    }
    __syncthreads();
    if (!amLast) return;

    // ---- finalize (one block of 128 threads; loops k=0,1 over bm = tid+128k) ----
    __shared__ float  areaSh[256];
    __shared__ double redA[2];
    __shared__ double redB[2];

#pragma unroll
    for (int k = 0; k < 2; ++k) {
        const int t = tid + k * 128;
        const float s0 = size_[t * 3 + 0];
        const float s1 = size_[t * 3 + 1];
        const float s2 = size_[t * 3 + 2];
        const float inner = powf(s0 * s1, 1.6f) * (1.0f / 3.0f)
                          + powf(s0 * s2, 1.6f) * (1.0f / 3.0f)
                          + powf(s1 * s2, 1.6f) * (1.0f / 3.0f);
        areaSh[t] = kFourPi * powf(inner, 0.625f);
    }
    __syncthreads();

    double t_acc = 0.0;
#pragma unroll
    for (int k = 0; k < 2; ++k) {
        const int t  = tid + k * 128;
        const int fb = t >> 4;
        float asum = 0.0f;
#pragma unroll
        for (int mm = 0; mm < 16; ++mm) asum += areaSh[fb * 16 + mm];
        const float anorm = 16.0f * areaSh[t] / asum;   // M * area / sum_m area
        t_acc += (double)(d2sum[t] * (1.0f / 128.0f)) * (double)probs[t] * (double)anorm;
    }
#pragma unroll
    for (int off = 32; off > 0; off >>= 1)
        t_acc += __shfl_down(t_acc, off, 64);
    if (lane == 0) redA[wid] = t_acc;

    double u = 0.0;
    {
        const float pv0 = __hip_atomic_load(&partial[tid],
                                            __ATOMIC_ACQUIRE, __HIP_MEMORY_SCOPE_AGENT);
        const float pv1 = __hip_atomic_load(&partial[tid + 128],
                                            __ATOMIC_ACQUIRE, __HIP_MEMORY_SCOPE_AGENT);
        u = (double)pv0 + (double)pv1;
    }
#pragma unroll
    for (int off = 32; off > 0; off >>= 1)
        u += __shfl_down(u, off, 64);
    if (lane == 0) redB[wid] = u;

    __syncthreads();
    if (tid == 0) {
        const double prim_to_pcl = (redA[0] + redA[1]) / 256.0;    // /(B*M)
        const double pcl_to_prim = (redB[0] + redB[1]) / 32768.0;  // /(B*N)
        out[0] = (float)(pcl_to_prim + prim_to_pcl);
        out[1] = (float)pcl_to_prim;
        out[2] = (float)prim_to_pcl;
        out[3] = 0.0f;
    }
}

// ---------------------------------------------------------------------------

extern "C" void kernel_launch(void* const* d_in, const int* in_sizes, int n_in,
                              void* d_out, int out_size, void* d_ws, size_t ws_size,
                              hipStream_t stream) {
    const float* pcl   = (const float*)d_in[0];  // (B,N,M,3)
    const float* prim  = (const float*)d_in[1];  // (B,M,S,3)
    const float* size_ = (const float*)d_in[2];  // (B,M,3)
    const float* probs = (const float*)d_in[3];  // (B,M)
    float* out = (float*)d_out;

    float* d1             = (float*)d_ws;             // 256*2048 floats (2 MiB)
    float* d2sum          = d1 + (size_t)256 * NN;    // 256
    float* partial        = d2sum + 256;              // 256
    unsigned int* counter = (unsigned int*)(partial + 256);

    fused_dist_kernel<<<BB * MM, 1024, 0, stream>>>(pcl, prim, d1, d2sum, counter);
    p2p_final_kernel<<<256, 128, 0, stream>>>(d1, probs, size_, d2sum, partial, counter, out);
}